// Round 1
// baseline (589.855 us; speedup 1.0000x reference)
//
#include <hip/hip_runtime.h>

// Problem constants
// x: (16, 64, 224, 224) f32, pw/pb: (64,16,16) f32, comp: (128,3,3) f32
// out: (16, 128, 222, 222) f32
// Key identity: conv kernel is channel-broadcast =>
//   out[b,o,i,j] = sum_{kh,kw} comp[o,kh,kw] * s[b,i+kh,j+kw]
//   s[b,h,w]     = sum_c ( x[b,c,h,w]*pw[c,h%16,w%16] + pb[c,h%16,w%16] )

#define NB 16
#define NC 64
#define NH 224
#define NW 224
#define NO 128
#define OH 222
#define OW 222

// ---------------- Stage 1: channel reduction -> s (16,224,224) ----------------
// One thread per float4 of s. Total quads = 16*224*56 = 200704 = 784 blocks * 256.
__global__ __launch_bounds__(256) void chansum_kernel(
    const float* __restrict__ x, const float* __restrict__ pw,
    const float* __restrict__ pb, float* __restrict__ s)
{
    int q   = blockIdx.x * 256 + threadIdx.x;      // [0, 200704)
    int w4  = q % 56;
    int tmp = q / 56;
    int h   = tmp % NH;
    int b   = tmp / NH;
    int w0  = w4 * 4;
    int hp  = h & 15;
    int wq  = w0 & 15;                             // 0,4,8,12 -> float4-aligned

    const float4* xp  = (const float4*)(x + (((size_t)b * NC) * NH + h) * NW + w0);
    const float4* pwp = (const float4*)(pw + hp * 16 + wq);
    const float4* pbp = (const float4*)(pb + hp * 16 + wq);

    float4 acc = make_float4(0.f, 0.f, 0.f, 0.f);
    #pragma unroll 8
    for (int c = 0; c < NC; ++c) {
        float4 xv  = xp[(size_t)c * (NH * NW / 4)];   // stride 224*224 floats
        float4 pwv = pwp[c * 64];                     // stride 256 floats
        float4 pbv = pbp[c * 64];
        acc.x = fmaf(xv.x, pwv.x, acc.x) + pbv.x;
        acc.y = fmaf(xv.y, pwv.y, acc.y) + pbv.y;
        acc.z = fmaf(xv.z, pwv.z, acc.z) + pbv.z;
        acc.w = fmaf(xv.w, pwv.w, acc.w) + pbv.w;
    }
    ((float4*)s)[q] = acc;
}

// ---------------- Stage 2: 3x3 conv, 128 output channels ----------------
// Block per (b, i) output row; thread per j-pair (111 pairs of OW=222).
// s values held in registers across all 128 o; comp indexed wave-uniformly
// (scalar loads); float2 stores for 512 B/wave-store.
__global__ __launch_bounds__(128) void conv_kernel(
    const float* __restrict__ s, const float* __restrict__ comp,
    float* __restrict__ out)
{
    int bi = blockIdx.x;          // b*222 + i
    int b  = bi / OH;
    int i  = bi - b * OH;
    int jp = threadIdx.x;
    if (jp >= OW / 2) return;

    float r[3][4];
    #pragma unroll
    for (int kh = 0; kh < 3; ++kh) {
        const float2* sp = (const float2*)(s + (((size_t)b * NH) + i + kh) * NW + 2 * jp);
        float2 lo = sp[0], hi = sp[1];
        r[kh][0] = lo.x; r[kh][1] = lo.y; r[kh][2] = hi.x; r[kh][3] = hi.y;
    }

    float2* outp = (float2*)out + ((size_t)b * NO * OH + i) * (OW / 2) + jp;
    const size_t ostride = (size_t)OH * (OW / 2);   // 24642 float2 per o

    #pragma unroll 4
    for (int o = 0; o < NO; ++o) {
        const float* cw = comp + o * 9;             // wave-uniform -> s_load
        float a0 = 0.f, a1 = 0.f;
        #pragma unroll
        for (int kh = 0; kh < 3; ++kh) {
            float c0 = cw[kh * 3 + 0], c1 = cw[kh * 3 + 1], c2 = cw[kh * 3 + 2];
            a0 = fmaf(r[kh][0], c0, a0);
            a0 = fmaf(r[kh][1], c1, a0);
            a0 = fmaf(r[kh][2], c2, a0);
            a1 = fmaf(r[kh][1], c0, a1);
            a1 = fmaf(r[kh][2], c1, a1);
            a1 = fmaf(r[kh][3], c2, a1);
        }
        outp[(size_t)o * ostride] = make_float2(a0, a1);
    }
}

// ---------------- Fallback: fused single kernel (no workspace) ----------------
// Only used if ws_size can't hold s (3.2 MB). Re-reads x with 3x redundancy.
__global__ __launch_bounds__(128) void fused_kernel(
    const float* __restrict__ x, const float* __restrict__ pw,
    const float* __restrict__ pb, const float* __restrict__ comp,
    float* __restrict__ out)
{
    __shared__ float s[3 * NW];
    int bi = blockIdx.x;
    int b  = bi / OH;
    int i  = bi - b * OH;

    for (int p = threadIdx.x; p < 3 * NW; p += 128) {
        int rr = p / NW, w = p - rr * NW;
        int h  = i + rr;
        int hp = h & 15, wq = w & 15;
        const float* xp  = x + (((size_t)b * NC) * NH + h) * NW + w;
        const float* pwp = pw + hp * 16 + wq;
        const float* pbp = pb + hp * 16 + wq;
        float acc = 0.f;
        for (int c = 0; c < NC; ++c)
            acc = fmaf(xp[(size_t)c * NH * NW], pwp[c * 256], acc) + pbp[c * 256];
        s[p] = acc;
    }
    __syncthreads();

    int jp = threadIdx.x;
    if (jp >= OW / 2) return;

    float r[3][4];
    #pragma unroll
    for (int kh = 0; kh < 3; ++kh)
        #pragma unroll
        for (int m = 0; m < 4; ++m)
            r[kh][m] = s[kh * NW + 2 * jp + m];

    float2* outp = (float2*)out + ((size_t)b * NO * OH + i) * (OW / 2) + jp;
    const size_t ostride = (size_t)OH * (OW / 2);

    #pragma unroll 4
    for (int o = 0; o < NO; ++o) {
        const float* cw = comp + o * 9;
        float a0 = 0.f, a1 = 0.f;
        #pragma unroll
        for (int kh = 0; kh < 3; ++kh) {
            float c0 = cw[kh * 3 + 0], c1 = cw[kh * 3 + 1], c2 = cw[kh * 3 + 2];
            a0 = fmaf(r[kh][0], c0, a0);
            a0 = fmaf(r[kh][1], c1, a0);
            a0 = fmaf(r[kh][2], c2, a0);
            a1 = fmaf(r[kh][1], c0, a1);
            a1 = fmaf(r[kh][2], c1, a1);
            a1 = fmaf(r[kh][3], c2, a1);
        }
        outp[(size_t)o * ostride] = make_float2(a0, a1);
    }
}

extern "C" void kernel_launch(void* const* d_in, const int* in_sizes, int n_in,
                              void* d_out, int out_size, void* d_ws, size_t ws_size,
                              hipStream_t stream) {
    const float* x    = (const float*)d_in[0];
    const float* pw   = (const float*)d_in[1];
    const float* pb   = (const float*)d_in[2];
    const float* comp = (const float*)d_in[3];
    float* out = (float*)d_out;

    const size_t s_bytes = (size_t)NB * NH * NW * sizeof(float);  // 3.2 MB
    if (ws_size >= s_bytes) {
        float* s = (float*)d_ws;
        chansum_kernel<<<(NB * NH * (NW / 4)) / 256, 256, 0, stream>>>(x, pw, pb, s);
        conv_kernel<<<NB * OH, 128, 0, stream>>>(s, comp, out);
    } else {
        fused_kernel<<<NB * OH, 128, 0, stream>>>(x, pw, pb, comp, out);
    }
}